// Round 3
// baseline (122.156 us; speedup 1.0000x reference)
//
#include <hip/hip_runtime.h>
#include <math.h>

#define K_DIM 4096
#define N_DIM 4096
#define ROWS_PER_BLOCK 8

typedef float f32x4 __attribute__((ext_vector_type(4)));

// ---------------- Kernel 1: c[k] = sum_n W[k][n]; block K_DIM also does bterm ----------------
__global__ void __launch_bounds__(256) colsum_kernel(const float* __restrict__ W,
                                                     const float* __restrict__ bias,
                                                     const float* __restrict__ subtract,
                                                     float* __restrict__ c,
                                                     float* __restrict__ bterm) {
    const int t = threadIdx.x;
    __shared__ float s[4];
    const int wave = t >> 6, lane = t & 63;

    if (blockIdx.x < K_DIM) {
        const int k = blockIdx.x;
        const float4* row = reinterpret_cast<const float4*>(W + (size_t)k * N_DIM);
        float acc = 0.f;
#pragma unroll
        for (int i = 0; i < N_DIM / 4 / 256; ++i) {   // 4 iterations
            float4 v = row[t + i * 256];
            acc += (v.x + v.y) + (v.z + v.w);
        }
#pragma unroll
        for (int off = 32; off > 0; off >>= 1) acc += __shfl_down(acc, off, 64);
        if (lane == 0) s[wave] = acc;
        __syncthreads();
        if (t == 0) c[k] = (s[0] + s[1]) + (s[2] + s[3]);
    } else {
        // bterm = (sum(bias) - sum(subtract)) / N
        float acc = 0.f;
        for (int i = t; i < N_DIM; i += 256) acc += bias[i] - subtract[i];
#pragma unroll
        for (int off = 32; off > 0; off >>= 1) acc += __shfl_down(acc, off, 64);
        if (lane == 0) s[wave] = acc;
        __syncthreads();
        if (t == 0) bterm[0] = ((s[0] + s[1]) + (s[2] + s[3])) * (1.0f / (float)N_DIM);
    }
}

// ---------------- Kernel 2: out[m][:] = x[m][:] + gelu(dot(x[m],c)/N + bterm) ----------------
// 8 rows per block; c in registers; double-buffered row prefetch; 1 barrier/row; nt stores.
__global__ void __launch_bounds__(256) rowfuse_kernel(const float* __restrict__ x,
                                                      const float* __restrict__ c,
                                                      const float* __restrict__ bterm,
                                                      float* __restrict__ out,
                                                      int M) {
    const int t = threadIdx.x;
    const int row0 = blockIdx.x * ROWS_PER_BLOCK;

    // Hoist c into registers (reused for all 8 rows)
    const float4* c4 = reinterpret_cast<const float4*>(c);
    float4 cv[4];
#pragma unroll
    for (int i = 0; i < 4; ++i) cv[i] = c4[t + i * 256];
    const float bt = bterm[0];

    const float4* xr = reinterpret_cast<const float4*>(x) + (size_t)row0 * (K_DIM / 4);
    f32x4* orow      = reinterpret_cast<f32x4*>(out)      + (size_t)row0 * (K_DIM / 4);

    __shared__ float s[ROWS_PER_BLOCK][4];   // per-row slots -> one barrier per row
    const int wave = t >> 6, lane = t & 63;

    float4 xv[2][4];
#pragma unroll
    for (int i = 0; i < 4; ++i) xv[0][i] = xr[t + i * 256];   // prefetch row 0

#pragma unroll
    for (int r = 0; r < ROWS_PER_BLOCK; ++r) {
        const int cur = r & 1, nxt = cur ^ 1;
        if (r + 1 < ROWS_PER_BLOCK) {
#pragma unroll
            for (int i = 0; i < 4; ++i)
                xv[nxt][i] = xr[(size_t)(r + 1) * (K_DIM / 4) + t + i * 256];
        }
        float acc = 0.f;
#pragma unroll
        for (int i = 0; i < 4; ++i)
            acc += xv[cur][i].x * cv[i].x + xv[cur][i].y * cv[i].y
                 + xv[cur][i].z * cv[i].z + xv[cur][i].w * cv[i].w;
#pragma unroll
        for (int off = 32; off > 0; off >>= 1) acc += __shfl_xor(acc, off, 64);
        if (lane == 0) s[r][wave] = acc;
        __syncthreads();

        // every thread computes gelu redundantly (cheap VALU, avoids 2nd barrier)
        float d = ((s[r][0] + s[r][1]) + (s[r][2] + s[r][3])) * (1.0f / (float)N_DIM) + bt;
        float inner = 0.7978845608028654f * (d + 0.044715f * d * d * d);
        float e  = __expf(2.0f * inner);
        float th = 1.0f - 2.0f / (e + 1.0f);
        float g  = 0.5f * d * (1.0f + th);

#pragma unroll
        for (int i = 0; i < 4; ++i) {
            f32x4 o;
            o.x = xv[cur][i].x + g;
            o.y = xv[cur][i].y + g;
            o.z = xv[cur][i].z + g;
            o.w = xv[cur][i].w + g;
            __builtin_nontemporal_store(o, &orow[(size_t)r * (K_DIM / 4) + t + i * 256]);
        }
    }
}

extern "C" void kernel_launch(void* const* d_in, const int* in_sizes, int n_in,
                              void* d_out, int out_size, void* d_ws, size_t ws_size,
                              hipStream_t stream) {
    const float* x        = (const float*)d_in[0];   // (M, K)
    const float* W        = (const float*)d_in[1];   // (K, N)
    const float* bias     = (const float*)d_in[2];   // (N,)
    const float* subtract = (const float*)d_in[3];   // (N,)
    float* out = (float*)d_out;

    float* c     = (float*)d_ws;          // K_DIM floats
    float* bterm = c + K_DIM;             // 1 float

    const int M = in_sizes[0] / K_DIM;    // 16384

    colsum_kernel<<<K_DIM + 1, 256, 0, stream>>>(W, bias, subtract, c, bterm);
    rowfuse_kernel<<<M / ROWS_PER_BLOCK, 256, 0, stream>>>(x, c, bterm, out, M);
}